// Round 11
// baseline (212.498 us; speedup 1.0000x reference)
//
#include <hip/hip_runtime.h>

#define NNODES 50000
#define NEDGES 800000
#define HD 128            // HEADS*OUT_DIM
#define NEG 0.2f
#define SCAN_BLOCKS ((NNODES + 255) / 256)   // 196
#define MTILE 128
#define LDW 136           // bf16 row stride in LDS
#define MAXD 64           // per-node LDS cache cap in gat_node
#define NZERO (NNODES + SCAN_BLOCKS)         // deg + scan-state zero region
#define ZBLKS ((NZERO + 255) / 256)          // 197

typedef __attribute__((ext_vector_type(8))) short short8;
typedef __attribute__((ext_vector_type(4))) float floatx4;

static __device__ inline unsigned short f2bf(float f) {
    unsigned u = __float_as_uint(f);
    return (unsigned short)((u + 0x7FFF + ((u >> 16) & 1)) >> 16);
}
static __device__ inline float bf2f(unsigned short u) {
    return __uint_as_float(((unsigned)u) << 16);
}
static __device__ inline float lrelu_exp(float a) {
    a = (a > 0.f) ? a : NEG * a;
    return __expf(a);
}

// ---------------------------------------------------------------------------
// Kernel 1: h(bf16) = x @ W^T via bf16 MFMA, MTILE=128 (halves W staging
// traffic vs 64). 4 waves; wave owns 2 m-tiles x 8 n-tiles (64 MFMAs).
// First ZBLKS blocks also zero deg+scan state (stream-ordered before gat_deg).
// Epilogue bounces C through LDS for coalesced 16B h stores.
// ---------------------------------------------------------------------------
__global__ __launch_bounds__(256) void gat_gemm(
    const float* __restrict__ x, const float* __restrict__ W,
    const float* __restrict__ att_src, const float* __restrict__ att_dst,
    unsigned short* __restrict__ h, float* __restrict__ asrc,
    float* __restrict__ adst, int* __restrict__ zero_region)
{
    __shared__ unsigned short Wl[128 * LDW];
    __shared__ unsigned short xl[MTILE * LDW];
    const int t = threadIdx.x;
    const int rowBase = blockIdx.x * MTILE;

    // fold-in: zero deg + scan state (tiny, coalesced)
    if (blockIdx.x < ZBLKS) {
        int zi = blockIdx.x * 256 + t;
        if (zi < NZERO) zero_region[zi] = 0;
    }

    for (int idx = t * 4; idx < 128 * 128; idx += 1024) {
        int r = idx >> 7, c = idx & 127;
        float4 v = *(const float4*)(W + idx);
        ushort4 u;
        u.x = f2bf(v.x); u.y = f2bf(v.y); u.z = f2bf(v.z); u.w = f2bf(v.w);
        *(ushort4*)(Wl + r * LDW + c) = u;
    }
    for (int idx = t * 4; idx < MTILE * 128; idx += 1024) {
        int r = idx >> 7, c = idx & 127;
        int g = rowBase + r;
        float4 v = make_float4(0.f, 0.f, 0.f, 0.f);
        if (g < NNODES) v = *(const float4*)(x + (size_t)g * 128 + c);
        ushort4 u;
        u.x = f2bf(v.x); u.y = f2bf(v.y); u.z = f2bf(v.z); u.w = f2bf(v.w);
        *(ushort4*)(xl + r * LDW + c) = u;
    }
    __syncthreads();

    const int wave = t >> 6;
    const int lane = t & 63;
    const int c16  = lane & 15;
    const int quad = lane >> 4;

    floatx4 acc[2][8];
#pragma unroll
    for (int mt = 0; mt < 2; mt++)
#pragma unroll
        for (int nt = 0; nt < 8; nt++) acc[mt][nt] = (floatx4)(0.f);

#pragma unroll
    for (int kc = 0; kc < 4; kc++) {
        short8 av0 = *(const short8*)(xl + (wave * 32 + c16) * LDW + kc * 32 + quad * 8);
        short8 av1 = *(const short8*)(xl + (wave * 32 + 16 + c16) * LDW + kc * 32 + quad * 8);
#pragma unroll
        for (int nt = 0; nt < 8; nt++) {
            short8 bv = *(const short8*)(Wl + (nt * 16 + c16) * LDW + kc * 32 + quad * 8);
            acc[0][nt] = __builtin_amdgcn_mfma_f32_16x16x32_bf16(av0, bv, acc[0][nt], 0, 0, 0);
            acc[1][nt] = __builtin_amdgcn_mfma_f32_16x16x32_bf16(av1, bv, acc[1][nt], 0, 0, 0);
        }
    }

    float As[8], Ad[8];
#pragma unroll
    for (int nt = 0; nt < 8; nt++) {
        As[nt] = att_src[nt * 16 + c16];
        Ad[nt] = att_dst[nt * 16 + c16];
    }
#pragma unroll
    for (int mt = 0; mt < 2; mt++) {
#pragma unroll
        for (int r = 0; r < 4; r++) {
            const int gr = rowBase + wave * 32 + mt * 16 + quad * 4 + r;
#pragma unroll
            for (int hh = 0; hh < 4; hh++) {
                float ps = acc[mt][2 * hh][r] * As[2 * hh] + acc[mt][2 * hh + 1][r] * As[2 * hh + 1];
                float pd = acc[mt][2 * hh][r] * Ad[2 * hh] + acc[mt][2 * hh + 1][r] * Ad[2 * hh + 1];
#pragma unroll
                for (int m = 8; m >= 1; m >>= 1) {
                    ps += __shfl_xor(ps, m, 64);
                    pd += __shfl_xor(pd, m, 64);
                }
                if (c16 == 0 && gr < NNODES) {
                    asrc[gr * 4 + hh] = ps;
                    adst[gr * 4 + hh] = pd;
                }
            }
        }
    }

    __syncthreads();
#pragma unroll
    for (int mt = 0; mt < 2; mt++)
#pragma unroll
        for (int r = 0; r < 4; r++) {
            const int lr = wave * 32 + mt * 16 + quad * 4 + r;
#pragma unroll
            for (int nt = 0; nt < 8; nt++)
                xl[lr * LDW + nt * 16 + c16] = f2bf(acc[mt][nt][r]);
        }
    __syncthreads();
    for (int idx = t * 8; idx < MTILE * 128; idx += 2048) {
        int r = idx >> 7, c = idx & 127;
        int g = rowBase + r;
        if (g < NNODES)
            *(short8*)(h + (size_t)g * HD + c) = *(const short8*)(xl + r * LDW + c);
    }
}

// ---------------------------------------------------------------------------
// Kernel 2: degree histogram. Returned old value = edge's in-bucket rank.
// ---------------------------------------------------------------------------
__global__ __launch_bounds__(256) void gat_deg(
    const int* __restrict__ ei, int* __restrict__ deg, int* __restrict__ rank)
{
    int e = blockIdx.x * 256 + threadIdx.x;
    int d = ei[NEDGES + e];
    rank[e] = atomicAdd(deg + d, 1);
}

// ---------------------------------------------------------------------------
// Kernel 3: single-pass exclusive scan (decoupled lookback). 196 blocks, all
// co-resident on 256 CUs -> forward progress guaranteed. state pre-zeroed by
// gat_gemm. Flags: 0=unpublished, A=aggregate, P=inclusive-prefix.
// ---------------------------------------------------------------------------
#define FLAG_A (1u << 30)
#define FLAG_P (2u << 30)
#define VALMASK (FLAG_A - 1u)

__global__ __launch_bounds__(256) void gat_scan(
    const int* __restrict__ deg, int* __restrict__ coff,
    unsigned int* __restrict__ state)
{
    __shared__ int sh[256];
    __shared__ int s_base;
    const int t = threadIdx.x;
    const int b = blockIdx.x;
    const int i = b * 256 + t;
    int v = (i < NNODES) ? deg[i] : 0;
    sh[t] = v;
    __syncthreads();
    for (int off = 1; off < 256; off <<= 1) {
        int u = (t >= off) ? sh[t - off] : 0;
        __syncthreads();
        sh[t] += u;
        __syncthreads();
    }
    const int agg = sh[255];
    if (t == 0) {
        if (b == 0) {
            atomicExch(&state[0], FLAG_P | (unsigned)agg);
            s_base = 0;
        } else {
            atomicExch(&state[b], FLAG_A | (unsigned)agg);
            int run = 0;
            int j = b - 1;
            while (j >= 0) {
                unsigned s = atomicAdd(&state[j], 0u);   // device-scope load
                unsigned f = s & ~VALMASK;
                if (f == 0u) continue;                    // spin: not published
                run += (int)(s & VALMASK);
                if (f == FLAG_P) break;
                j--;
            }
            atomicExch(&state[b], FLAG_P | (unsigned)(run + agg));
            s_base = run;
        }
    }
    __syncthreads();
    if (i < NNODES) coff[i] = s_base + sh[t] - v;
    if (i == 0) coff[NNODES] = NEDGES;
}

// ---------------------------------------------------------------------------
// Kernel 4: CSR fill — 4B src scatter only.
// ---------------------------------------------------------------------------
__global__ __launch_bounds__(256) void gat_fill(
    const int* __restrict__ ei, const int* __restrict__ rank,
    const int* __restrict__ coff, int* __restrict__ csr_src)
{
    int e = blockIdx.x * 256 + threadIdx.x;
    int s = ei[e], d = ei[NEDGES + e];
    csr_src[coff[d] + rank[e]] = s;
}

// ---------------------------------------------------------------------------
// Kernel 5: per-node. Phase 1: gather asrc[src] (L2-resident), compute exp
// weights, sum per head, stash (src,w4) in LDS. Phase 2: normalize + gather
// h rows, 4-way unroll (R8 form — 8-way measured slower). 32 lanes/node.
// ---------------------------------------------------------------------------
__global__ __launch_bounds__(256) void gat_node(
    const int* __restrict__ coff, const int* __restrict__ csr_src,
    const float* __restrict__ asrc, const float* __restrict__ adst,
    const unsigned short* __restrict__ h, const float* __restrict__ bias,
    float* __restrict__ out, float* __restrict__ ssum)
{
    __shared__ int   sh_src[8 * MAXD];
    __shared__ float sh_w[8 * MAXD * 4];
    int t = threadIdx.x;
    int node8 = t >> 5;
    int n = blockIdx.x * 8 + node8;
    int k = t & 31;
    int head = k >> 3;
    int beg = coff[n], end = coff[n + 1];
    const float4 bn = *(const float4*)(adst + n * 4);

    float4 sum = make_float4(0.f, 0.f, 0.f, 0.f);
    for (int j = beg + k; j < end; j += 32) {
        int s = csr_src[j];
        float4 a = *(const float4*)(asrc + s * 4);
        float4 wv;
        wv.x = lrelu_exp(a.x + bn.x);
        wv.y = lrelu_exp(a.y + bn.y);
        wv.z = lrelu_exp(a.z + bn.z);
        wv.w = lrelu_exp(a.w + bn.w);
        sum.x += wv.x; sum.y += wv.y; sum.z += wv.z; sum.w += wv.w;
        int i = j - beg;
        if (i < MAXD) {
            sh_src[node8 * MAXD + i] = s;
            *(float4*)(sh_w + (node8 * MAXD + i) * 4) = wv;
        }
    }
#pragma unroll
    for (int m = 16; m >= 1; m >>= 1) {
        sum.x += __shfl_xor(sum.x, m, 64);
        sum.y += __shfl_xor(sum.y, m, 64);
        sum.z += __shfl_xor(sum.z, m, 64);
        sum.w += __shfl_xor(sum.w, m, 64);
    }
    if (k == 0) *(float4*)(ssum + n * 4) = sum;
    float rs[4];
    rs[0] = 1.f / (sum.x + 1e-16f);
    rs[1] = 1.f / (sum.y + 1e-16f);
    rs[2] = 1.f / (sum.z + 1e-16f);
    rs[3] = 1.f / (sum.w + 1e-16f);
    const float rsel = rs[head];
    __syncthreads();

    const int cnt = end - beg;
    const int lim = (cnt < MAXD) ? cnt : MAXD;
    const int base = node8 * MAXD;
    float4 acc = *(const float4*)(bias + k * 4);
    float4 acc2 = make_float4(0.f, 0.f, 0.f, 0.f);
    int i = 0;
    for (; i + 4 <= lim; i += 4) {
        int s0 = sh_src[base + i];
        int s1 = sh_src[base + i + 1];
        int s2 = sh_src[base + i + 2];
        int s3 = sh_src[base + i + 3];
        float w0 = sh_w[(base + i) * 4 + head] * rsel;
        float w1 = sh_w[(base + i + 1) * 4 + head] * rsel;
        float w2 = sh_w[(base + i + 2) * 4 + head] * rsel;
        float w3 = sh_w[(base + i + 3) * 4 + head] * rsel;
        ushort4 u0 = *(const ushort4*)(h + (size_t)s0 * HD + k * 4);
        ushort4 u1 = *(const ushort4*)(h + (size_t)s1 * HD + k * 4);
        ushort4 u2 = *(const ushort4*)(h + (size_t)s2 * HD + k * 4);
        ushort4 u3 = *(const ushort4*)(h + (size_t)s3 * HD + k * 4);
        acc.x  = fmaf(bf2f(u0.x), w0, acc.x);
        acc.y  = fmaf(bf2f(u0.y), w0, acc.y);
        acc.z  = fmaf(bf2f(u0.z), w0, acc.z);
        acc.w  = fmaf(bf2f(u0.w), w0, acc.w);
        acc2.x = fmaf(bf2f(u1.x), w1, acc2.x);
        acc2.y = fmaf(bf2f(u1.y), w1, acc2.y);
        acc2.z = fmaf(bf2f(u1.z), w1, acc2.z);
        acc2.w = fmaf(bf2f(u1.w), w1, acc2.w);
        acc.x  = fmaf(bf2f(u2.x), w2, acc.x);
        acc.y  = fmaf(bf2f(u2.y), w2, acc.y);
        acc.z  = fmaf(bf2f(u2.z), w2, acc.z);
        acc.w  = fmaf(bf2f(u2.w), w2, acc.w);
        acc2.x = fmaf(bf2f(u3.x), w3, acc2.x);
        acc2.y = fmaf(bf2f(u3.y), w3, acc2.y);
        acc2.z = fmaf(bf2f(u3.z), w3, acc2.z);
        acc2.w = fmaf(bf2f(u3.w), w3, acc2.w);
    }
    for (; i < lim; i++) {
        int s0 = sh_src[base + i];
        float w0 = sh_w[(base + i) * 4 + head] * rsel;
        ushort4 u0 = *(const ushort4*)(h + (size_t)s0 * HD + k * 4);
        acc.x = fmaf(bf2f(u0.x), w0, acc.x);
        acc.y = fmaf(bf2f(u0.y), w0, acc.y);
        acc.z = fmaf(bf2f(u0.z), w0, acc.z);
        acc.w = fmaf(bf2f(u0.w), w0, acc.w);
    }
    for (int j = beg + MAXD; j < end; j++) {        // rare overflow fallback
        int s0 = csr_src[j];
        float4 a = *(const float4*)(asrc + s0 * 4);
        float w4[4];
        w4[0] = lrelu_exp(a.x + bn.x);
        w4[1] = lrelu_exp(a.y + bn.y);
        w4[2] = lrelu_exp(a.z + bn.z);
        w4[3] = lrelu_exp(a.w + bn.w);
        float w0 = w4[head] * rsel;
        ushort4 u0 = *(const ushort4*)(h + (size_t)s0 * HD + k * 4);
        acc.x = fmaf(bf2f(u0.x), w0, acc.x);
        acc.y = fmaf(bf2f(u0.y), w0, acc.y);
        acc.z = fmaf(bf2f(u0.z), w0, acc.z);
        acc.w = fmaf(bf2f(u0.w), w0, acc.w);
    }
    acc.x += acc2.x; acc.y += acc2.y; acc.z += acc2.z; acc.w += acc2.w;
    *(float4*)(out + (size_t)n * HD + k * 4) = acc;
}

// ---------------------------------------------------------------------------
// Kernel 6: alpha_pooled, edge-order; recompute exp from L2-resident arrays.
// ---------------------------------------------------------------------------
__global__ __launch_bounds__(256) void gat_apool(
    const int* __restrict__ ei, const float* __restrict__ asrc,
    const float* __restrict__ adst, const float* __restrict__ ssum,
    float* __restrict__ apool)
{
    int e = blockIdx.x * 256 + threadIdx.x;
    int s = ei[e], d = ei[NEDGES + e];
    float4 a  = *(const float4*)(asrc + s * 4);
    float4 b  = *(const float4*)(adst + d * 4);
    float4 sv = *(const float4*)(ssum + d * 4);
    float w0 = lrelu_exp(a.x + b.x) / (sv.x + 1e-16f);
    float w1 = lrelu_exp(a.y + b.y) / (sv.y + 1e-16f);
    float w2 = lrelu_exp(a.z + b.z) / (sv.z + 1e-16f);
    float w3 = lrelu_exp(a.w + b.w) / (sv.w + 1e-16f);
    apool[e] = 0.25f * (w0 + w1 + w2 + w3);
}

// ---------------------------------------------------------------------------
extern "C" void kernel_launch(void* const* d_in, const int* in_sizes, int n_in,
                              void* d_out, int out_size, void* d_ws, size_t ws_size,
                              hipStream_t stream)
{
    const float* x       = (const float*)d_in[0];
    const int*   ei      = (const int*)d_in[1];
    const float* W       = (const float*)d_in[2];
    const float* att_src = (const float*)d_in[3];
    const float* att_dst = (const float*)d_in[4];
    const float* bias    = (const float*)d_in[5];

    float* out   = (float*)d_out;                    // (N,128)
    float* apool = out + (size_t)NNODES * HD;        // (E,)

    // workspace layout (16B-aligned chunks); deg+state adjacent for fused zero
    unsigned short* h = (unsigned short*)d_ws;            // N*128 bf16
    float* asrc   = (float*)(h + (size_t)NNODES * HD);    // N*4
    float* adst   = asrc + NNODES * 4;               // N*4
    float* ssum   = adst + NNODES * 4;               // N*4
    int*   deg    = (int*)(ssum + NNODES * 4);       // N
    unsigned int* state = (unsigned int*)(deg + NNODES); // SCAN_BLOCKS
    int*   coff   = (int*)(state + SCAN_BLOCKS);     // N+1
    int*   rank   = coff + NNODES + 1;               // E
    int*   csrsrc = rank + NEDGES;                   // E

    gat_gemm<<<(NNODES + MTILE - 1) / MTILE, 256, 0, stream>>>(
        x, W, att_src, att_dst, h, asrc, adst, deg);
    gat_deg<<<NEDGES / 256, 256, 0, stream>>>(ei, deg, rank);
    gat_scan<<<SCAN_BLOCKS, 256, 0, stream>>>(deg, coff, state);
    gat_fill<<<NEDGES / 256, 256, 0, stream>>>(ei, rank, coff, csrsrc);
    gat_node<<<NNODES / 8, 256, 0, stream>>>(coff, csrsrc, asrc, adst, h, bias, out, ssum);
    gat_apool<<<NEDGES / 256, 256, 0, stream>>>(ei, asrc, adst, ssum, apool);
}

// Round 12
// 207.209 us; speedup vs baseline: 1.0255x; 1.0255x over previous
//
#include <hip/hip_runtime.h>

#define NNODES 50000
#define NEDGES 800000
#define HD 128            // HEADS*OUT_DIM
#define NEG 0.2f
#define SCAN_BLOCKS ((NNODES + 255) / 256)   // 196
#define MTILE 64
#define LDW 136           // bf16 row stride in LDS
#define MAXD 64           // per-node LDS cache cap in gat_node

typedef __attribute__((ext_vector_type(8))) short short8;
typedef __attribute__((ext_vector_type(4))) float floatx4;

static __device__ inline unsigned short f2bf(float f) {
    unsigned u = __float_as_uint(f);
    return (unsigned short)((u + 0x7FFF + ((u >> 16) & 1)) >> 16);
}
static __device__ inline float bf2f(unsigned short u) {
    return __uint_as_float(((unsigned)u) << 16);
}
static __device__ inline float lrelu_exp(float a) {
    a = (a > 0.f) ? a : NEG * a;
    return __expf(a);
}

// ---------------------------------------------------------------------------
// Kernel 0: one-shot W fp32 -> bf16  (R8-proven config).
// ---------------------------------------------------------------------------
__global__ __launch_bounds__(256) void gat_wprep(
    const float* __restrict__ W, unsigned short* __restrict__ Wbf)
{
    int i = (blockIdx.x * 256 + threadIdx.x) * 4;   // 16 blocks
    float4 v = *(const float4*)(W + i);
    ushort4 u;
    u.x = f2bf(v.x); u.y = f2bf(v.y); u.z = f2bf(v.z); u.w = f2bf(v.w);
    *(ushort4*)(Wbf + i) = u;
}

// ---------------------------------------------------------------------------
// Kernel 1: h(bf16) = x @ W^T via bf16 MFMA (16x16x32), MTILE=64 (3 blk/CU),
// fused asrc/adst dots; epilogue bounces C through LDS for 16B h stores.
// ---------------------------------------------------------------------------
__global__ __launch_bounds__(256) void gat_gemm(
    const float* __restrict__ x, const unsigned short* __restrict__ Wbf,
    const float* __restrict__ att_src, const float* __restrict__ att_dst,
    unsigned short* __restrict__ h, float* __restrict__ asrc,
    float* __restrict__ adst)
{
    __shared__ unsigned short Wl[128 * LDW];
    __shared__ unsigned short xl[MTILE * LDW];
    const int t = threadIdx.x;
    const int rowBase = blockIdx.x * MTILE;

    for (int idx = t * 8; idx < 128 * 128; idx += 2048) {
        int r = idx >> 7, c = idx & 127;
        *(short8*)(Wl + r * LDW + c) = *(const short8*)(Wbf + idx);
    }
    for (int idx = t * 4; idx < MTILE * 128; idx += 1024) {
        int r = idx >> 7, c = idx & 127;
        int g = rowBase + r;
        float4 v = make_float4(0.f, 0.f, 0.f, 0.f);
        if (g < NNODES) v = *(const float4*)(x + (size_t)g * 128 + c);
        ushort4 u;
        u.x = f2bf(v.x); u.y = f2bf(v.y); u.z = f2bf(v.z); u.w = f2bf(v.w);
        *(ushort4*)(xl + r * LDW + c) = u;
    }
    __syncthreads();

    const int wave = t >> 6;
    const int lane = t & 63;
    const int c16  = lane & 15;
    const int quad = lane >> 4;

    floatx4 acc[8];
#pragma unroll
    for (int nt = 0; nt < 8; nt++) acc[nt] = (floatx4)(0.f);

#pragma unroll
    for (int kc = 0; kc < 4; kc++) {
        short8 av = *(const short8*)(xl + (wave * 16 + c16) * LDW + kc * 32 + quad * 8);
#pragma unroll
        for (int nt = 0; nt < 8; nt++) {
            short8 bv = *(const short8*)(Wl + (nt * 16 + c16) * LDW + kc * 32 + quad * 8);
            acc[nt] = __builtin_amdgcn_mfma_f32_16x16x32_bf16(av, bv, acc[nt], 0, 0, 0);
        }
    }

    float As[8], Ad[8];
#pragma unroll
    for (int nt = 0; nt < 8; nt++) {
        As[nt] = att_src[nt * 16 + c16];
        Ad[nt] = att_dst[nt * 16 + c16];
    }
#pragma unroll
    for (int r = 0; r < 4; r++) {
        const int gr = rowBase + wave * 16 + quad * 4 + r;
#pragma unroll
        for (int hh = 0; hh < 4; hh++) {
            float ps = acc[2 * hh][r] * As[2 * hh] + acc[2 * hh + 1][r] * As[2 * hh + 1];
            float pd = acc[2 * hh][r] * Ad[2 * hh] + acc[2 * hh + 1][r] * Ad[2 * hh + 1];
#pragma unroll
            for (int m = 8; m >= 1; m >>= 1) {
                ps += __shfl_xor(ps, m, 64);
                pd += __shfl_xor(pd, m, 64);
            }
            if (c16 == 0 && gr < NNODES) {
                asrc[gr * 4 + hh] = ps;
                adst[gr * 4 + hh] = pd;
            }
        }
    }

    __syncthreads();
#pragma unroll
    for (int r = 0; r < 4; r++) {
        const int lr = wave * 16 + quad * 4 + r;
#pragma unroll
        for (int nt = 0; nt < 8; nt++)
            xl[lr * LDW + nt * 16 + c16] = f2bf(acc[nt][r]);
    }
    __syncthreads();
    for (int idx = t * 8; idx < MTILE * 128; idx += 2048) {
        int r = idx >> 7, c = idx & 127;
        int g = rowBase + r;
        if (g < NNODES)
            *(short8*)(h + (size_t)g * HD + c) = *(const short8*)(xl + r * LDW + c);
    }
}

// ---------------------------------------------------------------------------
// Kernel 2: degree histogram. Returned old value = edge's in-bucket rank.
// ---------------------------------------------------------------------------
__global__ __launch_bounds__(256) void gat_deg(
    const int* __restrict__ ei, int* __restrict__ deg, int* __restrict__ rank)
{
    int e = blockIdx.x * 256 + threadIdx.x;
    int d = ei[NEDGES + e];
    rank[e] = atomicAdd(deg + d, 1);
}

// ---------------------------------------------------------------------------
// Hierarchical exclusive scan of deg -> coff (R8-proven 3-stage form).
// ---------------------------------------------------------------------------
__global__ __launch_bounds__(256) void gat_scan1(
    const int* __restrict__ deg, int* __restrict__ coff, int* __restrict__ bsum)
{
    __shared__ int sh[256];
    const int t = threadIdx.x;
    const int i = blockIdx.x * 256 + t;
    int v = (i < NNODES) ? deg[i] : 0;
    sh[t] = v;
    __syncthreads();
    for (int off = 1; off < 256; off <<= 1) {
        int u = (t >= off) ? sh[t - off] : 0;
        __syncthreads();
        sh[t] += u;
        __syncthreads();
    }
    if (i < NNODES) coff[i] = sh[t] - v;
    if (t == 255) bsum[blockIdx.x] = sh[255];
}

__global__ __launch_bounds__(256) void gat_scan2(int* __restrict__ bsum)
{
    __shared__ int sh[256];
    const int t = threadIdx.x;
    int v = (t < SCAN_BLOCKS) ? bsum[t] : 0;
    sh[t] = v;
    __syncthreads();
    for (int off = 1; off < 256; off <<= 1) {
        int u = (t >= off) ? sh[t - off] : 0;
        __syncthreads();
        sh[t] += u;
        __syncthreads();
    }
    if (t < SCAN_BLOCKS) bsum[t] = sh[t] - v;
}

__global__ __launch_bounds__(256) void gat_scan3(
    int* __restrict__ coff, const int* __restrict__ bsum)
{
    const int i = blockIdx.x * 256 + threadIdx.x;
    if (i < NNODES) coff[i] += bsum[blockIdx.x];
    if (i == 0) coff[NNODES] = NEDGES;
}

// ---------------------------------------------------------------------------
// Kernel 4: CSR fill — scatter (src, edge_id) as one 8B int2.
// ---------------------------------------------------------------------------
__global__ __launch_bounds__(256) void gat_fill(
    const int* __restrict__ ei, const int* __restrict__ rank,
    const int* __restrict__ coff, int2* __restrict__ csr)
{
    int e = blockIdx.x * 256 + threadIdx.x;
    int s = ei[e], d = ei[NEDGES + e];
    csr[coff[d] + rank[e]] = make_int2(s, e);
}

// ---------------------------------------------------------------------------
// Kernel 5: per-node, now also emits alpha_pooled (apool fused — kernel 6
// eliminated). Phase 1: gather asrc[src] (L2-resident), compute exp weights,
// sum per head, stash (src,e,w4) in LDS. Mid: write apool from stash.
// Phase 2: normalize + gather h rows, 4-way unroll. 32 lanes/node, 8/block.
// ---------------------------------------------------------------------------
__global__ __launch_bounds__(256) void gat_node(
    const int* __restrict__ coff, const int2* __restrict__ csr,
    const float* __restrict__ asrc, const float* __restrict__ adst,
    const unsigned short* __restrict__ h, const float* __restrict__ bias,
    float* __restrict__ out, float* __restrict__ apool)
{
    __shared__ int   sh_src[8 * MAXD];
    __shared__ int   sh_e[8 * MAXD];
    __shared__ float sh_w[8 * MAXD * 4];
    int t = threadIdx.x;
    int node8 = t >> 5;
    int n = blockIdx.x * 8 + node8;
    int k = t & 31;
    int head = k >> 3;
    int beg = coff[n], end = coff[n + 1];
    const float4 bn = *(const float4*)(adst + n * 4);

    // phase 1: weight compute + sums + LDS stash
    float4 sum = make_float4(0.f, 0.f, 0.f, 0.f);
    for (int j = beg + k; j < end; j += 32) {
        int2 se = csr[j];
        float4 a = *(const float4*)(asrc + se.x * 4);
        float4 wv;
        wv.x = lrelu_exp(a.x + bn.x);
        wv.y = lrelu_exp(a.y + bn.y);
        wv.z = lrelu_exp(a.z + bn.z);
        wv.w = lrelu_exp(a.w + bn.w);
        sum.x += wv.x; sum.y += wv.y; sum.z += wv.z; sum.w += wv.w;
        int i = j - beg;
        if (i < MAXD) {
            sh_src[node8 * MAXD + i] = se.x;
            sh_e[node8 * MAXD + i] = se.y;
            *(float4*)(sh_w + (node8 * MAXD + i) * 4) = wv;
        }
    }
#pragma unroll
    for (int m = 16; m >= 1; m >>= 1) {
        sum.x += __shfl_xor(sum.x, m, 64);
        sum.y += __shfl_xor(sum.y, m, 64);
        sum.z += __shfl_xor(sum.z, m, 64);
        sum.w += __shfl_xor(sum.w, m, 64);
    }
    float rs[4];
    rs[0] = 1.f / (sum.x + 1e-16f);
    rs[1] = 1.f / (sum.y + 1e-16f);
    rs[2] = 1.f / (sum.z + 1e-16f);
    rs[3] = 1.f / (sum.w + 1e-16f);
    const float rsel = rs[head];
    __syncthreads();

    const int cnt = end - beg;
    const int lim = (cnt < MAXD) ? cnt : MAXD;
    const int base = node8 * MAXD;

    // apool from stash (lanes stride the bucket)
    for (int i = k; i < lim; i += 32) {
        float4 wv = *(const float4*)(sh_w + (base + i) * 4);
        apool[sh_e[base + i]] =
            0.25f * (wv.x * rs[0] + wv.y * rs[1] + wv.z * rs[2] + wv.w * rs[3]);
    }

    // phase 2: gather h rows, 4-way unroll (R8-proven form)
    float4 acc = *(const float4*)(bias + k * 4);
    float4 acc2 = make_float4(0.f, 0.f, 0.f, 0.f);
    int i = 0;
    for (; i + 4 <= lim; i += 4) {
        int s0 = sh_src[base + i];
        int s1 = sh_src[base + i + 1];
        int s2 = sh_src[base + i + 2];
        int s3 = sh_src[base + i + 3];
        float w0 = sh_w[(base + i) * 4 + head] * rsel;
        float w1 = sh_w[(base + i + 1) * 4 + head] * rsel;
        float w2 = sh_w[(base + i + 2) * 4 + head] * rsel;
        float w3 = sh_w[(base + i + 3) * 4 + head] * rsel;
        ushort4 u0 = *(const ushort4*)(h + (size_t)s0 * HD + k * 4);
        ushort4 u1 = *(const ushort4*)(h + (size_t)s1 * HD + k * 4);
        ushort4 u2 = *(const ushort4*)(h + (size_t)s2 * HD + k * 4);
        ushort4 u3 = *(const ushort4*)(h + (size_t)s3 * HD + k * 4);
        acc.x  = fmaf(bf2f(u0.x), w0, acc.x);
        acc.y  = fmaf(bf2f(u0.y), w0, acc.y);
        acc.z  = fmaf(bf2f(u0.z), w0, acc.z);
        acc.w  = fmaf(bf2f(u0.w), w0, acc.w);
        acc2.x = fmaf(bf2f(u1.x), w1, acc2.x);
        acc2.y = fmaf(bf2f(u1.y), w1, acc2.y);
        acc2.z = fmaf(bf2f(u1.z), w1, acc2.z);
        acc2.w = fmaf(bf2f(u1.w), w1, acc2.w);
        acc.x  = fmaf(bf2f(u2.x), w2, acc.x);
        acc.y  = fmaf(bf2f(u2.y), w2, acc.y);
        acc.z  = fmaf(bf2f(u2.z), w2, acc.z);
        acc.w  = fmaf(bf2f(u2.w), w2, acc.w);
        acc2.x = fmaf(bf2f(u3.x), w3, acc2.x);
        acc2.y = fmaf(bf2f(u3.y), w3, acc2.y);
        acc2.z = fmaf(bf2f(u3.z), w3, acc2.z);
        acc2.w = fmaf(bf2f(u3.w), w3, acc2.w);
    }
    for (; i < lim; i++) {
        int s0 = sh_src[base + i];
        float w0 = sh_w[(base + i) * 4 + head] * rsel;
        ushort4 u0 = *(const ushort4*)(h + (size_t)s0 * HD + k * 4);
        acc.x = fmaf(bf2f(u0.x), w0, acc.x);
        acc.y = fmaf(bf2f(u0.y), w0, acc.y);
        acc.z = fmaf(bf2f(u0.z), w0, acc.z);
        acc.w = fmaf(bf2f(u0.w), w0, acc.w);
    }
    for (int j = beg + MAXD; j < end; j++) {        // rare overflow fallback
        int2 se = csr[j];
        float4 a = *(const float4*)(asrc + se.x * 4);
        float w4[4];
        w4[0] = lrelu_exp(a.x + bn.x);
        w4[1] = lrelu_exp(a.y + bn.y);
        w4[2] = lrelu_exp(a.z + bn.z);
        w4[3] = lrelu_exp(a.w + bn.w);
        if (k == 0)
            apool[se.y] = 0.25f * (w4[0] * rs[0] + w4[1] * rs[1] +
                                   w4[2] * rs[2] + w4[3] * rs[3]);
        float w0 = w4[head] * rsel;
        ushort4 u0 = *(const ushort4*)(h + (size_t)se.x * HD + k * 4);
        acc.x = fmaf(bf2f(u0.x), w0, acc.x);
        acc.y = fmaf(bf2f(u0.y), w0, acc.y);
        acc.z = fmaf(bf2f(u0.z), w0, acc.z);
        acc.w = fmaf(bf2f(u0.w), w0, acc.w);
    }
    acc.x += acc2.x; acc.y += acc2.y; acc.z += acc2.z; acc.w += acc2.w;
    *(float4*)(out + (size_t)n * HD + k * 4) = acc;
}

// ---------------------------------------------------------------------------
extern "C" void kernel_launch(void* const* d_in, const int* in_sizes, int n_in,
                              void* d_out, int out_size, void* d_ws, size_t ws_size,
                              hipStream_t stream)
{
    const float* x       = (const float*)d_in[0];
    const int*   ei      = (const int*)d_in[1];
    const float* W       = (const float*)d_in[2];
    const float* att_src = (const float*)d_in[3];
    const float* att_dst = (const float*)d_in[4];
    const float* bias    = (const float*)d_in[5];

    float* out   = (float*)d_out;                    // (N,128)
    float* apool = out + (size_t)NNODES * HD;        // (E,)

    // workspace layout (16B-aligned chunks)
    unsigned short* h = (unsigned short*)d_ws;            // N*128 bf16
    float* asrc   = (float*)(h + (size_t)NNODES * HD);    // N*4
    float* adst   = asrc + NNODES * 4;               // N*4
    int*   deg    = (int*)(adst + NNODES * 4);       // N
    int*   coff   = deg + NNODES;                    // N+1
    int*   rank   = coff + NNODES + 1;               // E
    int*   bsum   = rank + NEDGES;                   // SCAN_BLOCKS
    int2*  csr    = (int2*)(bsum + SCAN_BLOCKS + 2); // E (8B each)
    unsigned short* wbf = (unsigned short*)(csr + NEDGES); // 16384

    hipMemsetAsync(deg, 0, (size_t)NNODES * sizeof(int), stream);

    gat_wprep<<<16, 256, 0, stream>>>(W, wbf);
    gat_gemm<<<(NNODES + MTILE - 1) / MTILE, 256, 0, stream>>>(
        x, wbf, att_src, att_dst, h, asrc, adst);
    gat_deg<<<NEDGES / 256, 256, 0, stream>>>(ei, deg, rank);
    gat_scan1<<<SCAN_BLOCKS, 256, 0, stream>>>(deg, coff, bsum);
    gat_scan2<<<1, 256, 0, stream>>>(bsum);
    gat_scan3<<<SCAN_BLOCKS, 256, 0, stream>>>(coff, bsum);
    gat_fill<<<NEDGES / 256, 256, 0, stream>>>(ei, rank, coff, csr);
    gat_node<<<NNODES / 8, 256, 0, stream>>>(coff, csr, asrc, adst, h, bias, out, apool);
}